// Round 1
// baseline (470.894 us; speedup 1.0000x reference)
//
#include <hip/hip_runtime.h>

// LIF dual forward: x [T,B,N,C] f32, decay scalar.
// out = concat(spikes [T,B,N,C], vpool [T,B,C]) flat f32.
constexpr int T  = 16;
constexpr int B  = 32;
constexpr int N  = 196;
constexpr int C  = 512;
constexpr int C4 = C / 4;    // 128 float4 lanes cover C
constexpr int NPB = 4;       // n-rows per block

__global__ __launch_bounds__(C4 * NPB) void lif_dual_kernel(
    const float4* __restrict__ x,
    const float*  __restrict__ decay,
    float4* __restrict__ spikes,
    float*  __restrict__ vpool) {
  __shared__ float4 red[NPB][C4];  // 8 KB

  const int tx = threadIdx.x;                 // c4 index: 0..127
  const int ty = threadIdx.y;                 // n within block: 0..3
  const int n  = blockIdx.x * NPB + ty;       // 0..195
  const int b  = blockIdx.y;                  // 0..31

  const float d     = decay[0];
  const float inv_n = 1.0f / (float)N;

  float4 v = make_float4(0.f, 0.f, 0.f, 0.f);

  size_t idx = ((size_t)b * N + n) * C4 + tx;          // (t=0,b,n,c4) in float4 units
  const size_t tstride = (size_t)B * N * C4;

  for (int t = 0; t < T; ++t) {
    float4 xt = x[idx];

    // charge
    v.x = d * v.x + xt.x;
    v.y = d * v.y + xt.y;
    v.z = d * v.z + xt.z;
    v.w = d * v.w + xt.w;

    // pre-reset value for vpool
    float4 vp = v;

    // spike + hard reset
    float4 s;
    s.x = (v.x >= 1.0f) ? 1.0f : 0.0f;  v.x = (v.x >= 1.0f) ? 0.0f : v.x;
    s.y = (v.y >= 1.0f) ? 1.0f : 0.0f;  v.y = (v.y >= 1.0f) ? 0.0f : v.y;
    s.z = (v.z >= 1.0f) ? 1.0f : 0.0f;  v.z = (v.z >= 1.0f) ? 0.0f : v.z;
    s.w = (v.w >= 1.0f) ? 1.0f : 0.0f;  v.w = (v.w >= 1.0f) ? 0.0f : v.w;

    spikes[idx] = s;

    // block-level reduction over the NPB n-rows for vpool
    red[ty][tx] = vp;
    __syncthreads();
    if (ty == 0) {
      float4 a0 = red[0][tx];
      float4 a1 = red[1][tx];
      float4 a2 = red[2][tx];
      float4 a3 = red[3][tx];
      float* out = vpool + ((size_t)t * B + b) * C + (size_t)tx * 4;
      atomicAdd(out + 0, (a0.x + a1.x + a2.x + a3.x) * inv_n);
      atomicAdd(out + 1, (a0.y + a1.y + a2.y + a3.y) * inv_n);
      atomicAdd(out + 2, (a0.z + a1.z + a2.z + a3.z) * inv_n);
      atomicAdd(out + 3, (a0.w + a1.w + a2.w + a3.w) * inv_n);
    }
    __syncthreads();  // protect red[] before next t overwrites

    idx += tstride;
  }
}

extern "C" void kernel_launch(void* const* d_in, const int* in_sizes, int n_in,
                              void* d_out, int out_size, void* d_ws, size_t ws_size,
                              hipStream_t stream) {
  const float4* x     = (const float4*)d_in[0];
  const float*  decay = (const float*)d_in[1];

  float* out = (float*)d_out;
  const size_t spike_elems = (size_t)T * B * N * C;   // 51,380,224
  const size_t vpool_elems = (size_t)T * B * C;       // 262,144

  float4* spikes = (float4*)out;
  float*  vpool  = out + spike_elems;

  // vpool is accumulated with atomics; d_out is poisoned before every launch.
  hipMemsetAsync(vpool, 0, vpool_elems * sizeof(float), stream);

  dim3 block(C4, NPB);          // 128 x 4 = 512 threads
  dim3 grid(N / NPB, B);        // 49 x 32 = 1568 blocks
  lif_dual_kernel<<<grid, block, 0, stream>>>(x, decay, spikes, vpool);
}

// Round 2
// 391.505 us; speedup vs baseline: 1.2028x; 1.2028x over previous
//
#include <hip/hip_runtime.h>

// LIF dual forward: x [T,B,N,C] f32, decay scalar.
// out = concat(spikes [T,B,N,C] f32, vpool [T,B,C] f32) flat.
//
// Layout: one thread owns (b, 7 consecutive n-rows, 4 consecutive channels).
// Main loop: rows outer, t inner (fully unrolled so vpsum[16] stays in VGPRs).
// No barriers/atomics in the main loop; epilogue does LDS ty-reduction + 1.8M atomics.
constexpr int T   = 16;
constexpr int B   = 32;
constexpr int N   = 196;
constexpr int C   = 512;
constexpr int C4  = C / 4;     // 128 float4 lanes cover C
constexpr int TX  = 64;        // c4 lanes per block
constexpr int TY  = 4;         // n-groups per block
constexpr int RPT = 7;         // rows per thread
constexpr int NCHUNK = N / (TY * RPT);  // 7 blocks along n
constexpr int CCHUNK = C4 / TX;         // 2 blocks along c

__global__ __launch_bounds__(TX * TY) void lif_dual_kernel(
    const float4* __restrict__ x,
    const float*  __restrict__ decay,
    float4* __restrict__ spikes,
    float*  __restrict__ vpool) {
  __shared__ float4 red[TY][4][TX];   // 16 KB, reused across 4 t-chunks

  const int tx = threadIdx.x;              // 0..63
  const int ty = threadIdx.y;              // 0..3
  const int cc = blockIdx.x;               // 0..1
  const int nc = blockIdx.y;               // 0..6
  const int b  = blockIdx.z;               // 0..31

  const int c4    = cc * TX + tx;          // 0..127
  const int nbase = nc * (TY * RPT) + ty * RPT;

  const float d     = decay[0];
  const float inv_n = 1.0f / (float)N;

  float4 vpsum[T];
#pragma unroll
  for (int t = 0; t < T; ++t) vpsum[t] = make_float4(0.f, 0.f, 0.f, 0.f);

  const size_t tstride = (size_t)B * N * C4;   // float4 units

#pragma unroll 1
  for (int r = 0; r < RPT; ++r) {
    const int n = nbase + r;
    size_t idx = ((size_t)b * N + n) * C4 + c4;   // (t=0,b,n,c4)
    float4 v = make_float4(0.f, 0.f, 0.f, 0.f);

#pragma unroll
    for (int t = 0; t < T; ++t) {
      float4 xt = x[idx];

      v.x = d * v.x + xt.x;
      v.y = d * v.y + xt.y;
      v.z = d * v.z + xt.z;
      v.w = d * v.w + xt.w;

      vpsum[t].x += v.x;
      vpsum[t].y += v.y;
      vpsum[t].z += v.z;
      vpsum[t].w += v.w;

      float4 s;
      s.x = (v.x >= 1.0f) ? 1.0f : 0.0f;  v.x = (v.x >= 1.0f) ? 0.0f : v.x;
      s.y = (v.y >= 1.0f) ? 1.0f : 0.0f;  v.y = (v.y >= 1.0f) ? 0.0f : v.y;
      s.z = (v.z >= 1.0f) ? 1.0f : 0.0f;  v.z = (v.z >= 1.0f) ? 0.0f : v.z;
      s.w = (v.w >= 1.0f) ? 1.0f : 0.0f;  v.w = (v.w >= 1.0f) ? 0.0f : v.w;

      spikes[idx] = s;
      idx += tstride;
    }
  }

  // Epilogue: reduce vpsum over ty (4 groups) via LDS, chunked 4 t at a time,
  // then atomicAdd block partial into vpool. 16 atomics/thread total.
#pragma unroll 1
  for (int tc = 0; tc < T; tc += 4) {
#pragma unroll
    for (int j = 0; j < 4; ++j) red[ty][j][tx] = vpsum[tc + j];
    __syncthreads();

    // 256 threads <-> 256 items: (tj = ty, tx)
    float4 a0 = red[0][ty][tx];
    float4 a1 = red[1][ty][tx];
    float4 a2 = red[2][ty][tx];
    float4 a3 = red[3][ty][tx];
    float4 s;
    s.x = (a0.x + a1.x + a2.x + a3.x) * inv_n;
    s.y = (a0.y + a1.y + a2.y + a3.y) * inv_n;
    s.z = (a0.z + a1.z + a2.z + a3.z) * inv_n;
    s.w = (a0.w + a1.w + a2.w + a3.w) * inv_n;

    const int t = tc + ty;
    float* out = vpool + ((size_t)t * B + b) * C + (size_t)c4 * 4;
    atomicAdd(out + 0, s.x);
    atomicAdd(out + 1, s.y);
    atomicAdd(out + 2, s.z);
    atomicAdd(out + 3, s.w);
    __syncthreads();
  }
}

extern "C" void kernel_launch(void* const* d_in, const int* in_sizes, int n_in,
                              void* d_out, int out_size, void* d_ws, size_t ws_size,
                              hipStream_t stream) {
  const float4* x     = (const float4*)d_in[0];
  const float*  decay = (const float*)d_in[1];

  float* out = (float*)d_out;
  const size_t spike_elems = (size_t)T * B * N * C;   // 51,380,224
  const size_t vpool_elems = (size_t)T * B * C;       // 262,144

  float4* spikes = (float4*)out;
  float*  vpool  = out + spike_elems;

  // vpool accumulated with atomics; d_out is poisoned before every launch.
  hipMemsetAsync(vpool, 0, vpool_elems * sizeof(float), stream);

  dim3 block(TX, TY);                    // 64 x 4 = 256 threads
  dim3 grid(CCHUNK, NCHUNK, B);          // 2 x 7 x 32 = 448 blocks
  lif_dual_kernel<<<grid, block, 0, stream>>>(x, decay, spikes, vpool);
}